// Round 1
// baseline (26649.173 us; speedup 1.0000x reference)
//
#include <hip/hip_runtime.h>

#define TSTEPS 784
#define BATCH  128
#define HID    256
#define WPG    4     // workgroups per group
#define BG     2     // batches per group
#define ROWS   256   // gate rows per WG (64 cols x 4 gates)
#define COLS   64    // hidden columns per WG

// ---------------- prep: permute input, zero h0 and flags ----------------
__global__ void prep_kernel(const float* __restrict__ in, const int* __restrict__ perm,
                            float* __restrict__ xp, float* __restrict__ hbuf0,
                            int* __restrict__ flags) {
    int i = blockIdx.x * blockDim.x + threadIdx.x;
    const int n1 = TSTEPS * BATCH;   // xp elements
    const int n2 = BATCH * HID;      // h buffer 0
    if (i < n1) {
        int t = i >> 7, b = i & 127;
        xp[i] = in[b * TSTEPS + perm[t]];
    } else if (i < n1 + n2) {
        hbuf0[i - n1] = 0.f;
    } else if (i < n1 + n2 + 256) {
        flags[i - n1 - n2] = 0;
    }
}

// ---------------- main persistent LSTM kernel ----------------
// grid 256 x 1024. Group g = blockIdx>>2 handles batches [2g, 2g+2).
// WG wgi = blockIdx&3 owns hidden cols [wgi*64, wgi*64+64) and their 4 gate rows.
// Wave layout (16 waves): kw = wave&3 (k-slice of 64), rw = wave>>2 (gate),
// lane = column-within-slice. Each thread holds W_hh[row][kw*64 .. +64) in VGPRs.
__global__ __launch_bounds__(1024, 4) void lstm_kernel(
    const float* __restrict__ Whh, const float* __restrict__ Wih,
    const float* __restrict__ bih, const float* __restrict__ bhh,
    const float* __restrict__ xp, float* __restrict__ hbuf,
    int* __restrict__ flags)
{
    __shared__ float h_lds[BG * HID];          // 2 KB staged h for this group's batches
    __shared__ float part[BG * ROWS * 5];      // 10 KB k-slice partials (pad 5 vs 4: bank-safe)
    __shared__ float c_lds[BG * COLS];         // cell state (owned here, never leaves CU)
    __shared__ float bias_lds[ROWS];
    __shared__ float win_lds[ROWS];

    const int tid = threadIdx.x;
    const int g       = blockIdx.x >> 2;
    const int wgi     = blockIdx.x & 3;
    const int B0      = g * BG;
    const int colbase = wgi * COLS;

    const int wave = tid >> 6;
    const int lane = tid & 63;
    const int kw   = wave & 3;          // k-slice index (4 x 64 = 256)
    const int rw   = wave >> 2;         // gate index 0..3
    const int r_local = rw * 64 + lane; // 0..255 local gate-row
    const int grow = rw * 256 + colbase + lane; // global gate row in [0,1024)

    // ---- load this thread's 64 weights into registers (one-time) ----
    float wreg[64];
    {
        const float4* wp = (const float4*)(Whh + grow * HID + kw * 64);
        #pragma unroll
        for (int q = 0; q < 16; ++q) {
            float4 v = wp[q];
            wreg[4*q+0] = v.x; wreg[4*q+1] = v.y; wreg[4*q+2] = v.z; wreg[4*q+3] = v.w;
        }
    }
    if (tid < ROWS) {
        int gr = (tid >> 6) * 256 + colbase + (tid & 63);
        bias_lds[tid] = bih[gr] + bhh[gr];
        win_lds[tid]  = Wih[gr];
    }
    if (tid < BG * COLS) c_lds[tid] = 0.f;
    __syncthreads();

    int* gflags = flags + g * WPG;
    const int prod = (tid & 255) >> 6;  // producer WG of my staged h element

    for (int t = 0; t < TSTEPS; ++t) {
        // x_t prefetch for update threads (independent of h, hides latency)
        float xv = 0.f;
        if (tid < BG * COLS) xv = xp[t * BATCH + B0 + (tid >> 6)];

        // ---- stage h_t: poll producer flag, then load (2 buffers + monotonic
        // flags: flag>=t proves producer finished READING h_{t-1}, so the
        // same-parity overwrite it did is safe, and h_t is published). ----
        if (tid < BG * HID) {
            while (__hip_atomic_load(&gflags[prod], __ATOMIC_ACQUIRE,
                                     __HIP_MEMORY_SCOPE_AGENT) < t) { }
            const float* hsrc = hbuf + (t & 1) * (BATCH * HID);
            int b = tid >> 8, k = tid & 255;
            h_lds[tid] = __hip_atomic_load(&hsrc[(B0 + b) * HID + k],
                                           __ATOMIC_RELAXED, __HIP_MEMORY_SCOPE_AGENT);
        }
        __syncthreads();

        // ---- dot: wave-uniform broadcast reads of h, weights from VGPRs ----
        float acc0 = 0.f, acc1 = 0.f;
        {
            const float4* h0 = (const float4*)(h_lds + kw * 64);
            const float4* h1 = (const float4*)(h_lds + HID + kw * 64);
            #pragma unroll
            for (int q = 0; q < 16; ++q) {
                float4 a = h0[q];
                float4 c = h1[q];
                acc0 = fmaf(wreg[4*q+0], a.x, acc0);
                acc1 = fmaf(wreg[4*q+0], c.x, acc1);
                acc0 = fmaf(wreg[4*q+1], a.y, acc0);
                acc1 = fmaf(wreg[4*q+1], c.y, acc1);
                acc0 = fmaf(wreg[4*q+2], a.z, acc0);
                acc1 = fmaf(wreg[4*q+2], c.z, acc1);
                acc0 = fmaf(wreg[4*q+3], a.w, acc0);
                acc1 = fmaf(wreg[4*q+3], c.w, acc1);
            }
        }
        part[r_local * 5 + kw]          = acc0;   // batch 0
        part[(ROWS + r_local) * 5 + kw] = acc1;   // batch 1
        __syncthreads();

        // ---- LSTM pointwise update (2 waves), write h slice, publish ----
        if (tid < BG * COLS) {
            int b = tid >> 6, j = tid & 63;
            float gp[4];
            #pragma unroll
            for (int gg = 0; gg < 4; ++gg) {
                int rl = gg * 64 + j;
                const float* pp = &part[(b * ROWS + rl) * 5];
                gp[gg] = ((pp[0] + pp[1]) + (pp[2] + pp[3]))
                         + win_lds[rl] * xv + bias_lds[rl];
            }
            float iv = 1.f / (1.f + __expf(-gp[0]));
            float fv = 1.f / (1.f + __expf(-gp[1]));
            float gv = 2.f / (1.f + __expf(-2.f * gp[2])) - 1.f;
            float ov = 1.f / (1.f + __expf(-gp[3]));
            float cn = fv * c_lds[tid] + iv * gv;
            c_lds[tid] = cn;
            float tc = 2.f / (1.f + __expf(-2.f * cn)) - 1.f;
            float hn = ov * tc;
            float* hdst = hbuf + ((t + 1) & 1) * (BATCH * HID);
            __hip_atomic_store(&hdst[(B0 + b) * HID + colbase + j], hn,
                               __ATOMIC_RELAXED, __HIP_MEMORY_SCOPE_AGENT);
        }
        __syncthreads();
        if (tid == 0) {
            __threadfence();  // publish this WG's h slice before the flag
            __hip_atomic_store(&gflags[wgi], t + 1, __ATOMIC_RELEASE,
                               __HIP_MEMORY_SCOPE_AGENT);
        }
    }
}

// ---------------- final linear: out = h_784 @ lin_W.T + lin_b ----------------
__global__ void out_kernel(const float* __restrict__ hbuf, const float* __restrict__ linW,
                           const float* __restrict__ linb, float* __restrict__ out) {
    __shared__ float hl[HID];
    int b = blockIdx.x;
    // T=784 is even -> final h lives in parity-0 buffer
    for (int k = threadIdx.x; k < HID; k += blockDim.x) hl[k] = hbuf[b * HID + k];
    __syncthreads();
    if (threadIdx.x < 10) {
        int n = threadIdx.x;
        float acc = linb[n];
        for (int k = 0; k < HID; ++k) acc = fmaf(hl[k], linW[n * HID + k], acc);
        out[b * 10 + n] = acc;
    }
}

extern "C" void kernel_launch(void* const* d_in, const int* in_sizes, int n_in,
                              void* d_out, int out_size, void* d_ws, size_t ws_size,
                              hipStream_t stream) {
    const float* inputs = (const float*)d_in[0];
    const int*   perm   = (const int*)d_in[1];
    const float* Wih    = (const float*)d_in[2];
    const float* Whh    = (const float*)d_in[3];
    const float* bih    = (const float*)d_in[4];
    const float* bhh    = (const float*)d_in[5];
    const float* linW   = (const float*)d_in[6];
    const float* linb   = (const float*)d_in[7];
    float* out = (float*)d_out;

    // d_ws layout: hbuf[2][128][256] f32 | xp[784][128] f32 | flags[256] int
    float* hbuf = (float*)d_ws;
    float* xp   = hbuf + 2 * BATCH * HID;
    int*   flags = (int*)(xp + TSTEPS * BATCH);

    const int ntot = TSTEPS * BATCH + BATCH * HID + 256;
    prep_kernel<<<(ntot + 255) / 256, 256, 0, stream>>>(inputs, perm, xp, hbuf, flags);
    lstm_kernel<<<256, 1024, 0, stream>>>(Whh, Wih, bih, bhh, xp, hbuf, flags);
    out_kernel<<<BATCH, 64, 0, stream>>>(hbuf, linW, linb, out);
}

// Round 2
// 3594.677 us; speedup vs baseline: 7.4135x; 7.4135x over previous
//
#include <hip/hip_runtime.h>

#define TSTEPS 784
#define BATCH  128
#define HID    256
#define WPG    8     // workgroups per group
#define BG     4     // batches per group
#define NGRP   (BATCH / BG)          // 32 groups
#define COLS   32    // hidden cols owned per WG
#define RLOC   128   // local gate rows per WG (4 gates x 32 cols)

// ---------------- prep: permute input (x transposed to [b][t]) ----------------
__global__ void prep_x(const float* __restrict__ in, const int* __restrict__ perm,
                       float* __restrict__ xp) {
    int b = blockIdx.x;
    for (int t = threadIdx.x; t < TSTEPS; t += blockDim.x)
        xp[b * TSTEPS + t] = in[b * TSTEPS + perm[t]];
}

__global__ void prep_zero(float* __restrict__ hbuf, int* __restrict__ flags) {
    int i = blockIdx.x * blockDim.x + threadIdx.x;
    if (i < BATCH * HID) hbuf[i] = 0.f;          // parity-0 buffer = h0
    int j = i - BATCH * HID;
    if (j >= 0 && j < 256) flags[j] = 0;
}

// ---------------- main persistent LSTM kernel ----------------
// grid 256 x 1024. group g = blockIdx>>3 owns batches [4g,4g+4).
// WG wgi = blockIdx&7 owns hidden cols [32*wgi, 32*wgi+32) (all 4 gates).
// thread: r = tid>>3 in [0,128) local gate-row (gate=r>>5, col=r&31),
//         s = tid&7 k-slice of 32 (k in [32s,32s+32)). 32 weights in 8 float4
//         regs, rotate-stored so h reads are bank-conflict-free.
__global__ __launch_bounds__(1024, 4) void lstm_kernel(
    const float* __restrict__ Whh, const float* __restrict__ Wih,
    const float* __restrict__ bih, const float* __restrict__ bhh,
    const float* __restrict__ xp, float* __restrict__ hbuf,
    int* __restrict__ flags)
{
    __shared__ float h_lds[BG * HID];            // 4 KB: staged h_t (4 batches)
    __shared__ float gate_lds[BG * 132];         // padded stride 132
    __shared__ float x_lds[BG * TSTEPS];         // 12.25 KB
    __shared__ float c_lds[BG * COLS];
    __shared__ float bias_lds[RLOC];
    __shared__ float win_lds[RLOC];

    const int tid = threadIdx.x;
    const int g       = blockIdx.x >> 3;
    const int wgi     = blockIdx.x & 7;
    const int B0      = g * BG;
    const int colbase = wgi * COLS;

    const int r = tid >> 3;                  // local gate-row 0..127
    const int s = tid & 7;                   // k-slice
    const int R = (r >> 5) * 256 + colbase + (r & 31);   // global gate row

    // ---- one-time loads ----
    // rotate-store: wreg[d] holds weight quad with local index (d+s)&7
    float4 w0, w1, w2, w3, w4, w5, w6, w7;
    {
        const float4* wp = (const float4*)(Whh + R * HID + s * 32);
        w0 = wp[(0 + s) & 7]; w1 = wp[(1 + s) & 7];
        w2 = wp[(2 + s) & 7]; w3 = wp[(3 + s) & 7];
        w4 = wp[(4 + s) & 7]; w5 = wp[(5 + s) & 7];
        w6 = wp[(6 + s) & 7]; w7 = wp[(7 + s) & 7];
    }
    if (tid < RLOC) {
        int gr = (tid >> 5) * 256 + colbase + (tid & 31);
        bias_lds[tid] = bih[gr] + bhh[gr];
        win_lds[tid]  = Wih[gr];
    }
    #pragma unroll
    for (int b = 0; b < BG; ++b)
        if (tid < TSTEPS) x_lds[b * TSTEPS + tid] = xp[(B0 + b) * TSTEPS + tid];
    if (tid < BG * COLS) c_lds[tid] = 0.f;
    __syncthreads();

    int* gflags = flags + g * WPG;

    for (int t = 0; t < TSTEPS; ++t) {
        // ---- wait for all 8 producers of h_t (relaxed poll: no cache inv) ----
        if (tid < WPG) {
            while (__hip_atomic_load(&gflags[tid], __ATOMIC_RELAXED,
                                     __HIP_MEMORY_SCOPE_AGENT) < t) { }
        }
        __syncthreads();
        // ---- stage h_t (relaxed agent atomics read the coherent point) ----
        {
            int b = tid >> 8, k = tid & 255;
            const float* hsrc = hbuf + (t & 1) * (BATCH * HID);
            h_lds[tid] = __hip_atomic_load(&hsrc[(B0 + b) * HID + k],
                                           __ATOMIC_RELAXED, __HIP_MEMORY_SCOPE_AGENT);
        }
        __syncthreads();

        // ---- dot: weights in VGPRs, h via rotated bank-conflict-free b128 ----
        float a0 = 0.f, a1 = 0.f, a2 = 0.f, a3 = 0.f;
        const float* hbase = h_lds + s * 32;
        #define DOT_STEP(d, wd)                                              \
        {                                                                    \
            int off = (((d) + s) & 7) * 4;                                   \
            float4 hq0 = *(const float4*)(hbase + off);                      \
            float4 hq1 = *(const float4*)(hbase + 256 + off);                \
            float4 hq2 = *(const float4*)(hbase + 512 + off);                \
            float4 hq3 = *(const float4*)(hbase + 768 + off);                \
            a0 = fmaf(wd.x, hq0.x, a0); a0 = fmaf(wd.y, hq0.y, a0);          \
            a0 = fmaf(wd.z, hq0.z, a0); a0 = fmaf(wd.w, hq0.w, a0);          \
            a1 = fmaf(wd.x, hq1.x, a1); a1 = fmaf(wd.y, hq1.y, a1);          \
            a1 = fmaf(wd.z, hq1.z, a1); a1 = fmaf(wd.w, hq1.w, a1);          \
            a2 = fmaf(wd.x, hq2.x, a2); a2 = fmaf(wd.y, hq2.y, a2);          \
            a2 = fmaf(wd.z, hq2.z, a2); a2 = fmaf(wd.w, hq2.w, a2);          \
            a3 = fmaf(wd.x, hq3.x, a3); a3 = fmaf(wd.y, hq3.y, a3);          \
            a3 = fmaf(wd.z, hq3.z, a3); a3 = fmaf(wd.w, hq3.w, a3);          \
        }
        DOT_STEP(0, w0) DOT_STEP(1, w1) DOT_STEP(2, w2) DOT_STEP(3, w3)
        DOT_STEP(4, w4) DOT_STEP(5, w5) DOT_STEP(6, w6) DOT_STEP(7, w7)
        #undef DOT_STEP

        // ---- k-reduce across the 8 slice-lanes (in-wave butterfly) ----
        #pragma unroll
        for (int m = 1; m < 8; m <<= 1) {
            a0 += __shfl_xor(a0, m, 64);
            a1 += __shfl_xor(a1, m, 64);
            a2 += __shfl_xor(a2, m, 64);
            a3 += __shfl_xor(a3, m, 64);
        }
        if (s == 0) gate_lds[0 * 132 + r] = a0;
        else if (s == 1) gate_lds[1 * 132 + r] = a1;
        else if (s == 2) gate_lds[2 * 132 + r] = a2;
        else if (s == 3) gate_lds[3 * 132 + r] = a3;
        __syncthreads();

        // ---- LSTM pointwise update (2 waves), publish h slice ----
        if (tid < BG * COLS) {
            int b = tid >> 5, j = tid & 31;
            float xv = x_lds[b * TSTEPS + t];
            float gp[4];
            #pragma unroll
            for (int q = 0; q < 4; ++q) {
                int rl = q * 32 + j;
                gp[q] = gate_lds[b * 132 + rl] + win_lds[rl] * xv + bias_lds[rl];
            }
            float iv = 1.f / (1.f + __expf(-gp[0]));
            float fv = 1.f / (1.f + __expf(-gp[1]));
            float gv = 2.f / (1.f + __expf(-2.f * gp[2])) - 1.f;
            float ov = 1.f / (1.f + __expf(-gp[3]));
            float cn = fv * c_lds[tid] + iv * gv;
            c_lds[tid] = cn;
            float tc = 2.f / (1.f + __expf(-2.f * cn)) - 1.f;
            float hn = ov * tc;
            float* hdst = hbuf + ((t + 1) & 1) * (BATCH * HID);
            __hip_atomic_store(&hdst[(B0 + b) * HID + colbase + j], hn,
                               __ATOMIC_RELAXED, __HIP_MEMORY_SCOPE_AGENT);
        }
        // order: h stores must be complete before the flag store (no L2
        // writeback needed — the atomic stores already went to the coherent
        // point). s_waitcnt is wave-wide; storing waves are 0-1, flag is wave 0.
        asm volatile("s_waitcnt vmcnt(0)" ::: "memory");
        __syncthreads();
        if (tid == 0)
            __hip_atomic_store(&gflags[wgi], t + 1, __ATOMIC_RELAXED,
                               __HIP_MEMORY_SCOPE_AGENT);
    }
}

// ---------------- final linear: out = h_784 @ lin_W.T + lin_b ----------------
__global__ void out_kernel(const float* __restrict__ hbuf, const float* __restrict__ linW,
                           const float* __restrict__ linb, float* __restrict__ out) {
    __shared__ float hl[HID];
    int b = blockIdx.x;
    for (int k = threadIdx.x; k < HID; k += blockDim.x) hl[k] = hbuf[b * HID + k];
    __syncthreads();
    if (threadIdx.x < 10) {
        int n = threadIdx.x;
        float acc = linb[n];
        for (int k = 0; k < HID; ++k) acc = fmaf(hl[k], linW[n * HID + k], acc);
        out[b * 10 + n] = acc;
    }
}

extern "C" void kernel_launch(void* const* d_in, const int* in_sizes, int n_in,
                              void* d_out, int out_size, void* d_ws, size_t ws_size,
                              hipStream_t stream) {
    const float* inputs = (const float*)d_in[0];
    const int*   perm   = (const int*)d_in[1];
    const float* Wih    = (const float*)d_in[2];
    const float* Whh    = (const float*)d_in[3];
    const float* bih    = (const float*)d_in[4];
    const float* bhh    = (const float*)d_in[5];
    const float* linW   = (const float*)d_in[6];
    const float* linb   = (const float*)d_in[7];
    float* out = (float*)d_out;

    // d_ws layout: hbuf[2][128][256] f32 | xp[128][784] f32 | flags[256] int
    float* hbuf  = (float*)d_ws;
    float* xp    = hbuf + 2 * BATCH * HID;
    int*   flags = (int*)(xp + BATCH * TSTEPS);

    prep_x<<<BATCH, 256, 0, stream>>>(inputs, perm, xp);
    prep_zero<<<(BATCH * HID + 256 + 255) / 256, 256, 0, stream>>>(hbuf, flags);
    lstm_kernel<<<NGRP * WPG, 1024, 0, stream>>>(Whh, Wih, bih, bhh, xp, hbuf, flags);
    out_kernel<<<BATCH, 64, 0, stream>>>(hbuf, linW, linb, out);
}

// Round 4
// 2244.140 us; speedup vs baseline: 11.8750x; 1.6018x over previous
//
#include <hip/hip_runtime.h>

#define TSTEPS 784
#define BATCH  128
#define HID    256
#define WPG    8     // workgroups per group
#define BG     4     // batches per group
#define NGRP   (BATCH / BG)          // 32 groups
#define COLS   32    // hidden cols owned per WG
#define RLOC   128   // local gate rows per WG (4 gates x 32 cols)
typedef unsigned long long u64;

// ---------------- prep: permute input (x transposed to [b][t]) ----------------
__global__ void prep_x(const float* __restrict__ in, const int* __restrict__ perm,
                       float* __restrict__ xp) {
    int b = blockIdx.x;
    for (int t = threadIdx.x; t < TSTEPS; t += blockDim.x)
        xp[b * TSTEPS + t] = in[b * TSTEPS + perm[t]];
}

// slots[parity][b][k]: hi32 = tag (step index whose h is stored), lo32 = f32 bits.
// parity0 init: tag=0, value=0.0f  -> the u64 0.  parity1 init: sentinel tag.
__global__ void prep_slots(u64* __restrict__ slots) {
    int i = blockIdx.x * blockDim.x + threadIdx.x;
    if (i < BATCH * HID)          slots[i] = 0ull;
    else if (i < 2 * BATCH * HID) slots[i] = 0xFFFFFFFF00000000ull;
}

// ---------------- main persistent LSTM kernel ----------------
// grid 256 x 1024. group g = blockIdx&31 (8 WGs of a group share an XCD under
// round-robin dispatch — perf heuristic only). WG wgi = blockIdx>>5 owns hidden
// cols [32*wgi, 32*wgi+32) (all 4 gates). thread: r = tid>>3 local gate-row
// (gate=r>>5, col=r&31), s = tid&7 k-slice of 32. 32 weights live in 8 float4
// VGPRs (pinned via asm), rotate-stored so h reads are bank-conflict-free.
__global__ __launch_bounds__(1024, 4) void lstm_kernel(
    const float* __restrict__ Whh, const float* __restrict__ Wih,
    const float* __restrict__ bih, const float* __restrict__ bhh,
    const float* __restrict__ xp, u64* __restrict__ slots)
{
    __shared__ float h_lds[BG * HID];            // 4 KB staged h_t
    __shared__ float gate_lds[BG * 132];         // activated gates, padded stride
    __shared__ float x_lds[BG * TSTEPS];         // 12.25 KB
    __shared__ float c_lds[BG * COLS];
    __shared__ float bias_lds[RLOC];
    __shared__ float win_lds[RLOC];

    const int tid = threadIdx.x;
    const int g       = blockIdx.x & 31;
    const int wgi     = blockIdx.x >> 5;
    const int B0      = g * BG;
    const int colbase = wgi * COLS;

    const int r = tid >> 3;                  // local gate-row 0..127
    const int s = tid & 7;                   // k-slice
    const int gate = r >> 5;                 // wave-uniform (8 r's per wave)
    const int R = gate * 256 + colbase + (r & 31);   // global gate row

    // ---- one-time loads; rotate-store: reg d holds quad index (d+s)&7 ----
    float4 w0, w1, w2, w3, w4, w5, w6, w7;
    {
        const float4* wp = (const float4*)(Whh + R * HID + s * 32);
        w0 = wp[(0 + s) & 7]; w1 = wp[(1 + s) & 7];
        w2 = wp[(2 + s) & 7]; w3 = wp[(3 + s) & 7];
        w4 = wp[(4 + s) & 7]; w5 = wp[(5 + s) & 7];
        w6 = wp[(6 + s) & 7]; w7 = wp[(7 + s) & 7];
    }
    // Pin in VGPRs: asm "writes" them, so the loads can't be sunk into the loop.
    // (macro param must NOT be named 'w' — it would substitute into the .w
    // member token: KEEP4(w7) -> w7.w7)
    #define KEEP4(V) asm volatile("" : "+v"((V).x), "+v"((V).y), "+v"((V).z), "+v"((V).w))
    KEEP4(w0); KEEP4(w1); KEEP4(w2); KEEP4(w3);
    KEEP4(w4); KEEP4(w5); KEEP4(w6); KEEP4(w7);
    #undef KEEP4

    if (tid < RLOC) {
        int gr = (tid >> 5) * 256 + colbase + (tid & 31);
        bias_lds[tid] = bih[gr] + bhh[gr];
        win_lds[tid]  = Wih[gr];
    }
    #pragma unroll
    for (int b = 0; b < BG; ++b)
        if (tid < TSTEPS) x_lds[b * TSTEPS + tid] = xp[(B0 + b) * TSTEPS + tid];
    if (tid < BG * COLS) c_lds[tid] = 0.f;
    __syncthreads();

    // poll target for this thread: element (pb, pk) of the group's h
    const int pb = tid >> 8, pk = tid & 255;
    u64* const slot0 = slots + (B0 + pb) * HID + pk;               // parity 0
    u64* const slot1 = slots + BATCH * HID + (B0 + pb) * HID + pk; // parity 1

    for (int t = 0; t < TSTEPS; ++t) {
        // ---- stage h_t: poll the tagged value directly (1 round trip) ----
        {
            u64* sp = (t & 1) ? slot1 : slot0;
            u64 v;
            do {
                v = __hip_atomic_load(sp, __ATOMIC_RELAXED, __HIP_MEMORY_SCOPE_AGENT);
            } while ((unsigned)(v >> 32) != (unsigned)t);
            h_lds[tid] = __uint_as_float((unsigned)v);
        }
        __syncthreads();

        // ---- dot: weights in VGPRs, h via rotated bank-conflict-free b128 ----
        float a0 = 0.f, a1 = 0.f, a2 = 0.f, a3 = 0.f;
        const float* hbase = h_lds + s * 32;
        #define DOT_STEP(d, wd)                                              \
        {                                                                    \
            int off = (((d) + s) & 7) * 4;                                   \
            float4 hq0 = *(const float4*)(hbase + off);                      \
            float4 hq1 = *(const float4*)(hbase + 256 + off);                \
            float4 hq2 = *(const float4*)(hbase + 512 + off);                \
            float4 hq3 = *(const float4*)(hbase + 768 + off);                \
            a0 = fmaf(wd.x, hq0.x, a0); a0 = fmaf(wd.y, hq0.y, a0);          \
            a0 = fmaf(wd.z, hq0.z, a0); a0 = fmaf(wd.w, hq0.w, a0);          \
            a1 = fmaf(wd.x, hq1.x, a1); a1 = fmaf(wd.y, hq1.y, a1);          \
            a1 = fmaf(wd.z, hq1.z, a1); a1 = fmaf(wd.w, hq1.w, a1);          \
            a2 = fmaf(wd.x, hq2.x, a2); a2 = fmaf(wd.y, hq2.y, a2);          \
            a2 = fmaf(wd.z, hq2.z, a2); a2 = fmaf(wd.w, hq2.w, a2);          \
            a3 = fmaf(wd.x, hq3.x, a3); a3 = fmaf(wd.y, hq3.y, a3);          \
            a3 = fmaf(wd.z, hq3.z, a3); a3 = fmaf(wd.w, hq3.w, a3);          \
        }
        DOT_STEP(0, w0) DOT_STEP(1, w1) DOT_STEP(2, w2) DOT_STEP(3, w3)
        DOT_STEP(4, w4) DOT_STEP(5, w5) DOT_STEP(6, w6) DOT_STEP(7, w7)
        #undef DOT_STEP

        // ---- k-reduce across the 8 slice-lanes (in-wave butterfly) ----
        #pragma unroll
        for (int m = 1; m < 8; m <<= 1) {
            a0 += __shfl_xor(a0, m, 64);
            a1 += __shfl_xor(a1, m, 64);
            a2 += __shfl_xor(a2, m, 64);
            a3 += __shfl_xor(a3, m, 64);
        }
        // lane s finishes batch s: add bias + w_in*x, apply gate nonlinearity
        // (gate is wave-uniform -> no divergence), write activated gate.
        if (s < BG) {
            float sum = (s == 0) ? a0 : (s == 1) ? a1 : (s == 2) ? a2 : a3;
            float xv = x_lds[s * TSTEPS + t];
            float full = fmaf(win_lds[r], xv, sum + bias_lds[r]);
            float act;
            if (gate == 2) act = 2.f / (1.f + __expf(-2.f * full)) - 1.f;  // tanh
            else           act = 1.f / (1.f + __expf(-full));              // sigmoid
            gate_lds[s * 132 + r] = act;
        }
        __syncthreads();

        // ---- c/h update (128 threads), publish tagged h (no fence needed) ----
        if (tid < BG * COLS) {
            int b = tid >> 5, j = tid & 31;
            float iv = gate_lds[b * 132 + j];
            float fv = gate_lds[b * 132 + 32 + j];
            float gv = gate_lds[b * 132 + 64 + j];
            float ov = gate_lds[b * 132 + 96 + j];
            float cn = fmaf(fv, c_lds[tid], iv * gv);
            c_lds[tid] = cn;
            float tc = 2.f / (1.f + __expf(-2.f * cn)) - 1.f;
            float hn = ov * tc;
            u64 val = ((u64)(unsigned)(t + 1) << 32) | (u64)__float_as_uint(hn);
            u64* dp = slots + ((t + 1) & 1) * (BATCH * HID)
                            + (B0 + b) * HID + colbase + j;
            __hip_atomic_store(dp, val, __ATOMIC_RELAXED, __HIP_MEMORY_SCOPE_AGENT);
        }
        // no trailing barrier: next poll/h_lds write is fenced by the two
        // barriers above (all h_lds readers passed the gate barrier).
    }
}

// ---------------- final linear: out = h_784 @ lin_W.T + lin_b ----------------
__global__ void out_kernel(const u64* __restrict__ slots, const float* __restrict__ linW,
                           const float* __restrict__ linb, float* __restrict__ out) {
    __shared__ float hl[HID];
    int b = blockIdx.x;
    // T=784 even -> final h is in parity-0 slots (tag 784), low 32 bits
    for (int k = threadIdx.x; k < HID; k += blockDim.x)
        hl[k] = __uint_as_float((unsigned)slots[b * HID + k]);
    __syncthreads();
    if (threadIdx.x < 10) {
        int n = threadIdx.x;
        float acc = linb[n];
        for (int k = 0; k < HID; ++k) acc = fmaf(hl[k], linW[n * HID + k], acc);
        out[b * 10 + n] = acc;
    }
}

extern "C" void kernel_launch(void* const* d_in, const int* in_sizes, int n_in,
                              void* d_out, int out_size, void* d_ws, size_t ws_size,
                              hipStream_t stream) {
    const float* inputs = (const float*)d_in[0];
    const int*   perm   = (const int*)d_in[1];
    const float* Wih    = (const float*)d_in[2];
    const float* Whh    = (const float*)d_in[3];
    const float* bih    = (const float*)d_in[4];
    const float* bhh    = (const float*)d_in[5];
    const float* linW   = (const float*)d_in[6];
    const float* linb   = (const float*)d_in[7];
    float* out = (float*)d_out;

    // d_ws layout: slots[2][128][256] u64 (512KB) | xp[128][784] f32 (401KB)
    u64*   slots = (u64*)d_ws;
    float* xp    = (float*)(slots + 2 * BATCH * HID);

    prep_x<<<BATCH, 256, 0, stream>>>(inputs, perm, xp);
    prep_slots<<<(2 * BATCH * HID + 255) / 256, 256, 0, stream>>>(slots);
    lstm_kernel<<<NGRP * WPG, 1024, 0, stream>>>(Whh, Wih, bih, bhh, xp, slots);
    out_kernel<<<BATCH, 64, 0, stream>>>(slots, linW, linb, out);
}